// Round 1
// baseline (99.948 us; speedup 1.0000x reference)
//
#include <hip/hip_runtime.h>
#include <stdint.h>

#define HW 4096
#define NC 128
#define BATCH 2

typedef __attribute__((ext_vector_type(8))) short bf16x8;
typedef __attribute__((ext_vector_type(4))) float f32x4;
typedef __attribute__((ext_vector_type(8))) unsigned short u16x8;

__device__ __forceinline__ unsigned short f32_to_bf16(float f) {
    union { float f; unsigned int u; } v; v.f = f;
    unsigned int u = v.u;
    unsigned int r = (u + 0x7FFFu + ((u >> 16) & 1u)) >> 16;
    return (unsigned short)r;
}

// Writes a_n and d = c_n - b_n, transposed to [b][pos][c] bf16, with the
// 16B-chunk XOR swizzle (chunk slot = chunk ^ (pos & 7)) baked into the
// global layout so the GEMM's LDS tiles are contiguous copies and the
// ds_read_b128 fragment reads are 2-way-conflict-free (free on gfx950).
__global__ __launch_bounds__(256) void norm_kernel(
    const float* __restrict__ A, const float* __restrict__ B,
    const float* __restrict__ Cc,
    unsigned short* __restrict__ anT, unsigned short* __restrict__ dT) {
    const int tid  = threadIdx.x;
    const int lane = tid & 63;   // position within 64-wide strip
    const int cp   = tid >> 6;   // channel quarter, 0..3 (one per wave)
    const int gp   = blockIdx.x * 64;          // 0..8191, step 64
    const int bb   = gp >> 12;                 // batch
    const int p    = (gp & (HW - 1)) + lane;   // position in [0,4096)
    const size_t base = (size_t)bb * NC * HW + p;  // + c*HW indexes x[b][c][p]
    const int c0 = cp * 32;

    float sa = 0.f, sb = 0.f, sc = 0.f;
#pragma unroll 8
    for (int k = 0; k < 32; ++k) {
        size_t idx = base + (size_t)(c0 + k) * HW;
        sa += fabsf(A[idx]); sb += fabsf(B[idx]); sc += fabsf(Cc[idx]);
    }
    __shared__ float red[3][4][64];
    red[0][cp][lane] = sa; red[1][cp][lane] = sb; red[2][cp][lane] = sc;
    __syncthreads();
    float na = red[0][0][lane] + red[0][1][lane] + red[0][2][lane] + red[0][3][lane];
    float nb = red[1][0][lane] + red[1][1][lane] + red[1][2][lane] + red[1][3][lane];
    float nc = red[2][0][lane] + red[2][1][lane] + red[2][2][lane] + red[2][3][lane];
    const float ra = 1.f / fmaxf(na, 1e-12f);
    const float rb = 1.f / fmaxf(nb, 1e-12f);
    const float rc = 1.f / fmaxf(nc, 1e-12f);

    const size_t obase = ((size_t)bb * HW + p) * NC;  // row of 128 bf16
    const int sw = p & 7;
#pragma unroll
    for (int c8 = 0; c8 < 4; ++c8) {
        u16x8 va, vd;
#pragma unroll
        for (int j = 0; j < 8; ++j) {
            size_t idx = base + (size_t)(c0 + c8 * 8 + j) * HW;
            va[j] = f32_to_bf16(A[idx] * ra);
            vd[j] = f32_to_bf16(Cc[idx] * rc - B[idx] * rb);
        }
        const int slot = ((cp * 4 + c8) ^ sw);
        *(u16x8*)(anT + obase + slot * 8) = va;
        *(u16x8*)(dT  + obase + slot * 8) = vd;
    }
}

// One block = 128x128 output tile of S = A_n^T * D for one batch.
// K = 128 (full channel dim) staged once into LDS; 2x2 wave grid, each wave
// 64x64 via 4x4 grid of 16x16x32 bf16 MFMAs. Epilogue: abs-sum -> shuffle
// reduce -> one atomicAdd of the pre-scaled partial. C/D register layout is
// irrelevant because we only reduce over the whole tile.
__global__ __launch_bounds__(256, 2) void simloss_kernel(
    const unsigned short* __restrict__ anT, const unsigned short* __restrict__ dT,
    float* __restrict__ out) {
    __shared__ uint4 smem4[4096];  // 64 KB: [0,2048) = A tile, [2048,4096) = B tile
    const int tid = threadIdx.x;
    const int bz  = blockIdx.z;
    const int m0  = blockIdx.y * 128;
    const int n0  = blockIdx.x * 128;
    const uint4* gA = (const uint4*)(anT + ((size_t)bz * HW + m0) * NC);
    const uint4* gB = (const uint4*)(dT  + ((size_t)bz * HW + n0) * NC);
#pragma unroll
    for (int i = 0; i < 8; ++i) {
        int idx = i * 256 + tid;       // 2048 uint4 per 32KB tile
        smem4[idx]        = gA[idx];
        smem4[2048 + idx] = gB[idx];
    }
    __syncthreads();

    const int ln   = tid & 63;
    const int wv   = tid >> 6;
    const int m16  = ln & 15;
    const int quad = ln >> 4;
    const int wr   = (wv >> 1) * 64;   // wave M offset in tile
    const int wc   = (wv & 1) * 64;    // wave N offset in tile
    const uint8_t* As = (const uint8_t*)smem4;
    const uint8_t* Bs = (const uint8_t*)(smem4 + 2048);

    f32x4 acc[4][4] = {};
#pragma unroll
    for (int ks = 0; ks < 4; ++ks) {
        const int chunk = ks * 4 + quad;
        const int slot  = chunk ^ (m16 & 7);   // row&7 == m16&7 (tiles are 16-aligned)
        bf16x8 af[4], bfr[4];
#pragma unroll
        for (int mi = 0; mi < 4; ++mi)
            af[mi] = *(const bf16x8*)(As + (wr + mi * 16 + m16) * 256 + slot * 16);
#pragma unroll
        for (int ni = 0; ni < 4; ++ni)
            bfr[ni] = *(const bf16x8*)(Bs + (wc + ni * 16 + m16) * 256 + slot * 16);
#pragma unroll
        for (int mi = 0; mi < 4; ++mi)
#pragma unroll
            for (int ni = 0; ni < 4; ++ni)
                acc[mi][ni] = __builtin_amdgcn_mfma_f32_16x16x32_bf16(
                    af[mi], bfr[ni], acc[mi][ni], 0, 0, 0);
    }

    float s = 0.f;
#pragma unroll
    for (int mi = 0; mi < 4; ++mi)
#pragma unroll
        for (int ni = 0; ni < 4; ++ni)
#pragma unroll
            for (int r = 0; r < 4; ++r)
                s += fabsf(acc[mi][ni][r]);
#pragma unroll
    for (int off = 32; off > 0; off >>= 1)
        s += __shfl_down(s, off);

    __syncthreads();                    // all waves done reading LDS; reuse it
    if (ln == 0) ((float*)smem4)[wv] = s;
    __syncthreads();
    if (tid == 0) {
        const float inv = 1.0f / ((float)BATCH * (float)HW * (float)HW);
        float t = ((float*)smem4)[0] + ((float*)smem4)[1] +
                  ((float*)smem4)[2] + ((float*)smem4)[3];
        atomicAdd(out, t * inv);
    }
}

extern "C" void kernel_launch(void* const* d_in, const int* in_sizes, int n_in,
                              void* d_out, int out_size, void* d_ws, size_t ws_size,
                              hipStream_t stream) {
    const float* A  = (const float*)d_in[0];
    const float* B  = (const float*)d_in[1];
    const float* Cc = (const float*)d_in[2];
    float* out = (float*)d_out;
    unsigned short* anT = (unsigned short*)d_ws;                       // 2 MB
    unsigned short* dT  = anT + (size_t)BATCH * HW * NC;               // 2 MB

    hipMemsetAsync(d_out, 0, sizeof(float), stream);
    norm_kernel<<<dim3(128), dim3(256), 0, stream>>>(A, B, Cc, anT, dT);
    simloss_kernel<<<dim3(32, 32, BATCH), dim3(256), 0, stream>>>(anT, dT, out);
}

// Round 2
// 95.179 us; speedup vs baseline: 1.0501x; 1.0501x over previous
//
#include <hip/hip_runtime.h>
#include <stdint.h>

#define HW 4096
#define NC 128
#define BATCH 2

typedef __attribute__((ext_vector_type(8))) short bf16x8;
typedef __attribute__((ext_vector_type(4))) float f32x4;
typedef __attribute__((ext_vector_type(8))) unsigned short u16x8;

__device__ __forceinline__ unsigned short f32_to_bf16(float f) {
    union { float f; unsigned int u; } v; v.f = f;
    unsigned int u = v.u;
    unsigned int r = (u + 0x7FFFu + ((u >> 16) & 1u)) >> 16;
    return (unsigned short)r;
}

// Single-pass L1-normalize + transpose. Each thread owns 16 channels of one
// position, held in registers (no second global read). Output layout:
// [b][pos][c] bf16 with 16B chunk swizzle slot = chunk ^ (pos & 15) baked in,
// so the GEMM's ds_read_b128 reads tile all 16 slots per 16-lane phase
// (2-way bank aliasing max = free on gfx950, m136).
__global__ __launch_bounds__(256) void norm_kernel(
    const float* __restrict__ A, const float* __restrict__ B,
    const float* __restrict__ Cc,
    unsigned short* __restrict__ anT, unsigned short* __restrict__ dT,
    float* __restrict__ out) {
    const int tid = threadIdx.x;
    if (blockIdx.x == 0 && tid == 0) *out = 0.f;  // replaces memset dispatch
    const int pl = tid & 31;            // position lane
    const int cp = tid >> 5;            // channel group 0..7 (16 ch each)
    const int gp = blockIdx.x * 32;     // global position base, 0..8191
    const int bb = gp >> 12;            // batch
    const int p  = (gp & (HW - 1)) + pl;
    const size_t base = (size_t)bb * NC * HW + p;   // + c*HW -> x[b][c][p]
    const int c0 = cp * 16;

    float va[16], vb[16], vc[16];
    float sa = 0.f, sb = 0.f, sc = 0.f;
#pragma unroll
    for (int k = 0; k < 16; ++k) {
        size_t idx = base + (size_t)(c0 + k) * HW;
        va[k] = A[idx]; vb[k] = B[idx]; vc[k] = Cc[idx];
        sa += fabsf(va[k]); sb += fabsf(vb[k]); sc += fabsf(vc[k]);
    }
    __shared__ float red[3][8][32];
    red[0][cp][pl] = sa; red[1][cp][pl] = sb; red[2][cp][pl] = sc;
    __syncthreads();
    float na = 0.f, nb = 0.f, nc = 0.f;
#pragma unroll
    for (int g = 0; g < 8; ++g) {
        na += red[0][g][pl]; nb += red[1][g][pl]; nc += red[2][g][pl];
    }
    const float ra = 1.f / fmaxf(na, 1e-12f);
    const float rb = 1.f / fmaxf(nb, 1e-12f);
    const float rc = 1.f / fmaxf(nc, 1e-12f);

    const size_t obase = ((size_t)bb * HW + p) * NC;  // 256 B row per position
    const int sw = p & 15;
#pragma unroll
    for (int c8 = 0; c8 < 2; ++c8) {
        u16x8 xa, xd;
#pragma unroll
        for (int j = 0; j < 8; ++j) {
            int k = c8 * 8 + j;
            xa[j] = f32_to_bf16(va[k] * ra);
            xd[j] = f32_to_bf16(vc[k] * rc - vb[k] * rb);
        }
        const int slot = (cp * 2 + c8) ^ sw;
        *(u16x8*)(anT + obase + slot * 8) = xa;
        *(u16x8*)(dT  + obase + slot * 8) = xd;
    }
}

// One block = 128x128 tile of S = A_n^T * D for one batch; K=128 in one LDS
// stage (64 KB, 2 blocks/CU). 2x2 wave grid, 64x64 per wave via 4x4 of
// 16x16x32 bf16 MFMA. Epilogue reduces |S| -> one atomicAdd; C/D register
// layout is irrelevant since we only reduce.
__global__ __launch_bounds__(256, 2) void simloss_kernel(
    const unsigned short* __restrict__ anT, const unsigned short* __restrict__ dT,
    float* __restrict__ out) {
    __shared__ uint4 smem4[4096];  // [0,2048)=A tile, [2048,4096)=B tile
    const int tid = threadIdx.x;
    const int bz  = blockIdx.z;
    const int m0  = blockIdx.y * 128;
    const int n0  = blockIdx.x * 128;
    const uint4* gA = (const uint4*)(anT + ((size_t)bz * HW + m0) * NC);
    const uint4* gB = (const uint4*)(dT  + ((size_t)bz * HW + n0) * NC);
#pragma unroll
    for (int i = 0; i < 8; ++i) {
        int idx = i * 256 + tid;   // 2048 uint4 per 32 KB tile
        smem4[idx]        = gA[idx];
        smem4[2048 + idx] = gB[idx];
    }
    __syncthreads();

    const int ln   = tid & 63;
    const int wv   = tid >> 6;
    const int m16  = ln & 15;
    const int quad = ln >> 4;
    const int wr   = (wv >> 1) * 64;
    const int wc   = (wv & 1) * 64;
    const uint8_t* As = (const uint8_t*)smem4;
    const uint8_t* Bs = (const uint8_t*)(smem4 + 2048);

    f32x4 acc[4][4] = {};
#pragma unroll
    for (int ks = 0; ks < 4; ++ks) {
        const int chunk = ks * 4 + quad;
        const int slot  = chunk ^ m16;   // full 4-bit XOR: 16-lane phase tiles all 16 slots
        bf16x8 af[4], bfr[4];
#pragma unroll
        for (int mi = 0; mi < 4; ++mi)
            af[mi] = *(const bf16x8*)(As + (wr + mi * 16 + m16) * 256 + slot * 16);
#pragma unroll
        for (int ni = 0; ni < 4; ++ni)
            bfr[ni] = *(const bf16x8*)(Bs + (wc + ni * 16 + m16) * 256 + slot * 16);
#pragma unroll
        for (int mi = 0; mi < 4; ++mi)
#pragma unroll
            for (int ni = 0; ni < 4; ++ni)
                acc[mi][ni] = __builtin_amdgcn_mfma_f32_16x16x32_bf16(
                    af[mi], bfr[ni], acc[mi][ni], 0, 0, 0);
    }

    float s = 0.f;
#pragma unroll
    for (int mi = 0; mi < 4; ++mi)
#pragma unroll
        for (int ni = 0; ni < 4; ++ni)
#pragma unroll
            for (int r = 0; r < 4; ++r)
                s += fabsf(acc[mi][ni][r]);
#pragma unroll
    for (int off = 32; off > 0; off >>= 1)
        s += __shfl_down(s, off);

    __syncthreads();
    if (ln == 0) ((float*)smem4)[wv] = s;
    __syncthreads();
    if (tid == 0) {
        const float inv = 1.0f / ((float)BATCH * (float)HW * (float)HW);
        float t = ((float*)smem4)[0] + ((float*)smem4)[1] +
                  ((float*)smem4)[2] + ((float*)smem4)[3];
        atomicAdd(out, t * inv);
    }
}

extern "C" void kernel_launch(void* const* d_in, const int* in_sizes, int n_in,
                              void* d_out, int out_size, void* d_ws, size_t ws_size,
                              hipStream_t stream) {
    const float* A  = (const float*)d_in[0];
    const float* B  = (const float*)d_in[1];
    const float* Cc = (const float*)d_in[2];
    float* out = (float*)d_out;
    unsigned short* anT = (unsigned short*)d_ws;                 // 2 MB
    unsigned short* dT  = anT + (size_t)BATCH * HW * NC;         // 2 MB

    norm_kernel<<<dim3(256), dim3(256), 0, stream>>>(A, B, Cc, anT, dT, out);
    simloss_kernel<<<dim3(32, 32, BATCH), dim3(256), 0, stream>>>(anT, dT, out);
}

// Round 3
// 79.901 us; speedup vs baseline: 1.2509x; 1.1912x over previous
//
#include <hip/hip_runtime.h>
#include <stdint.h>

#define HW 4096
#define NC 128
#define BATCH 2

typedef __attribute__((ext_vector_type(8))) short bf16x8;
typedef __attribute__((ext_vector_type(4))) float f32x4;
typedef __attribute__((ext_vector_type(8))) unsigned short u16x8;

__device__ __forceinline__ unsigned short f32_to_bf16(float f) {
    union { float f; unsigned int u; } v; v.f = f;
    unsigned int u = v.u;
    unsigned int r = (u + 0x7FFFu + ((u >> 16) & 1u)) >> 16;
    return (unsigned short)r;
}

// Async global->LDS, 16B per lane. Dest is wave-uniform base + lane*16 (m104):
// caller passes the wave-uniform LDS base; gptr is the per-lane global addr.
__device__ __forceinline__ void async_cp16(const void* g, void* s) {
    __builtin_amdgcn_global_load_lds(
        (const __attribute__((address_space(1))) uint32_t*)g,
        (__attribute__((address_space(3))) uint32_t*)s, 16, 0, 0);
}

// Single-pass L1-normalize + transpose to [b][pos][c] bf16 with the 16B-chunk
// XOR swizzle (slot = chunk ^ (pos & 15)) baked into the global layout.
// 512 threads: 32 positions x 16 channel-groups (8 ch each) -> each thread
// emits exactly one 16B chunk per output array.
__global__ __launch_bounds__(512) void norm_kernel(
    const float* __restrict__ A, const float* __restrict__ B,
    const float* __restrict__ Cc,
    unsigned short* __restrict__ anT, unsigned short* __restrict__ dT,
    float* __restrict__ out) {
    const int tid = threadIdx.x;
    if (blockIdx.x == 0 && tid == 0) *out = 0.f;  // replaces memset dispatch
    const int pl = tid & 31;            // position lane
    const int cg = tid >> 5;            // channel group 0..15 (8 ch each)
    const int gp = blockIdx.x * 32;     // 256 blocks x 32 positions
    const int bb = gp >> 12;
    const int p  = (gp & (HW - 1)) + pl;
    const size_t base = (size_t)bb * NC * HW + p;   // + c*HW -> x[b][c][p]
    const int c0 = cg * 8;

    float va[8], vb[8], vc[8];
    float sa = 0.f, sb = 0.f, sc = 0.f;
#pragma unroll
    for (int k = 0; k < 8; ++k) {
        size_t idx = base + (size_t)(c0 + k) * HW;
        va[k] = A[idx]; vb[k] = B[idx]; vc[k] = Cc[idx];
        sa += fabsf(va[k]); sb += fabsf(vb[k]); sc += fabsf(vc[k]);
    }
    __shared__ float red[3][16][32];
    red[0][cg][pl] = sa; red[1][cg][pl] = sb; red[2][cg][pl] = sc;
    __syncthreads();
    float na = 0.f, nb = 0.f, nc = 0.f;
#pragma unroll
    for (int g = 0; g < 16; ++g) {
        na += red[0][g][pl]; nb += red[1][g][pl]; nc += red[2][g][pl];
    }
    const float ra = 1.f / fmaxf(na, 1e-12f);
    const float rb = 1.f / fmaxf(nb, 1e-12f);
    const float rc = 1.f / fmaxf(nc, 1e-12f);

    const size_t obase = ((size_t)bb * HW + p) * NC;  // 256 B row per position
    const int slot = cg ^ (p & 15);
    u16x8 xa, xd;
#pragma unroll
    for (int j = 0; j < 8; ++j) {
        xa[j] = f32_to_bf16(va[j] * ra);
        xd[j] = f32_to_bf16(vc[j] * rc - vb[j] * rb);
    }
    *(u16x8*)(anT + obase + slot * 8) = xa;
    *(u16x8*)(dT  + obase + slot * 8) = xd;
}

// Persistent-block GEMM: 512 blocks, each owns one 128-row A panel (staged to
// LDS once) and loops over 4 consecutive 128-col B tiles. K=128 whole. 2x2
// wave grid, 64x64/wave via 4x4 of 16x16x32 bf16 MFMA. abs-sum epilogue,
// one atomicAdd per block. C/D register layout irrelevant (pure reduction).
__global__ __launch_bounds__(256, 2) void simloss_kernel(
    const unsigned short* __restrict__ anT, const unsigned short* __restrict__ dT,
    float* __restrict__ out) {
    __shared__ uint4 smem4[4096];  // [0,2048)=A panel 32KB, [2048,4096)=B tile 32KB
    const int tid = threadIdx.x;
    const int b   = blockIdx.x;          // 0..511
    const int bz  = b >> 8;              // batch
    const int my  = (b & 255) >> 3;      // m-tile 0..31
    const int ng  = b & 7;               // n-group: tiles ng*4 .. ng*4+3
    const char* gA = (const char*)(anT + ((size_t)bz * HW + my * 128) * NC);
    const char* gB0 = (const char*)(dT + ((size_t)bz * HW + ng * 4 * 128) * NC);

    const int wv  = tid >> 6;
    const int ln  = tid & 63;
    char* sA = (char*)smem4;
    char* sB = (char*)(smem4 + 2048);

    // Stage A panel (32 KB) + first B tile, async: 8 x 16B per thread each.
#pragma unroll
    for (int i = 0; i < 8; ++i) {
        const size_t goff = (size_t)(i * 256 + tid) * 16;
        const size_t loff = (size_t)i * 4096 + wv * 1024;  // wave-uniform base
        async_cp16(gA + goff, sA + loff);
        async_cp16(gB0 + goff, sB + loff);
    }
    __syncthreads();

    const int m16  = ln & 15;
    const int quad = ln >> 4;
    const int wr   = (wv >> 1) * 64;
    const int wc   = (wv & 1) * 64;

    float s = 0.f;
    for (int j = 0; j < 4; ++j) {
        f32x4 acc[4][4] = {};
#pragma unroll
        for (int ks = 0; ks < 4; ++ks) {
            const int chunk = ks * 4 + quad;
            const int slot  = chunk ^ m16;   // tiles all 16 slots per 16-lane phase
            bf16x8 af[4], bfr[4];
#pragma unroll
            for (int mi = 0; mi < 4; ++mi)
                af[mi] = *(const bf16x8*)(sA + (wr + mi * 16 + m16) * 256 + slot * 16);
#pragma unroll
            for (int ni = 0; ni < 4; ++ni)
                bfr[ni] = *(const bf16x8*)(sB + (wc + ni * 16 + m16) * 256 + slot * 16);
#pragma unroll
            for (int mi = 0; mi < 4; ++mi)
#pragma unroll
                for (int ni = 0; ni < 4; ++ni)
                    acc[mi][ni] = __builtin_amdgcn_mfma_f32_16x16x32_bf16(
                        af[mi], bfr[ni], acc[mi][ni], 0, 0, 0);
        }
#pragma unroll
        for (int mi = 0; mi < 4; ++mi)
#pragma unroll
            for (int ni = 0; ni < 4; ++ni)
#pragma unroll
                for (int r = 0; r < 4; ++r)
                    s += fabsf(acc[mi][ni][r]);

        __syncthreads();                 // all waves done reading B tile j
        if (j < 3) {
            const char* gBn = gB0 + (size_t)(j + 1) * 32768;
#pragma unroll
            for (int i = 0; i < 8; ++i) {
                const size_t goff = (size_t)(i * 256 + tid) * 16;
                const size_t loff = (size_t)i * 4096 + wv * 1024;
                async_cp16(gBn + goff, sB + loff);
            }
            __syncthreads();
        }
    }

#pragma unroll
    for (int off = 32; off > 0; off >>= 1)
        s += __shfl_down(s, off);
    if (ln == 0) ((float*)smem4)[wv] = s;
    __syncthreads();
    if (tid == 0) {
        const float inv = 1.0f / ((float)BATCH * (float)HW * (float)HW);
        float t = ((float*)smem4)[0] + ((float*)smem4)[1] +
                  ((float*)smem4)[2] + ((float*)smem4)[3];
        atomicAdd(out, t * inv);
    }
}

extern "C" void kernel_launch(void* const* d_in, const int* in_sizes, int n_in,
                              void* d_out, int out_size, void* d_ws, size_t ws_size,
                              hipStream_t stream) {
    const float* A  = (const float*)d_in[0];
    const float* B  = (const float*)d_in[1];
    const float* Cc = (const float*)d_in[2];
    float* out = (float*)d_out;
    unsigned short* anT = (unsigned short*)d_ws;                 // 2 MB
    unsigned short* dT  = anT + (size_t)BATCH * HW * NC;         // 2 MB

    norm_kernel<<<dim3(256), dim3(512), 0, stream>>>(A, B, Cc, anT, dT, out);
    simloss_kernel<<<dim3(512), dim3(256), 0, stream>>>(anT, dT, out);
}